// Round 4
// baseline (554.600 us; speedup 1.0000x reference)
//
#include <hip/hip_runtime.h>

// Guided filter, B=2, H=W=1024, C=3, K=4, R=16, EPS=0.01.
// gf(x) = Vblur33(Hblur33(x)) - x  (separable Gaussian, center tap removed),
// N(y,x) = rowW(x)*colW(y) - 1 computed in closed form per pixel.
// Workspace requirement: 50 planes * 4 MiB = 209,715,200 bytes.
//
// VT=8 for vertical blurs: VT=32 made the unrolled rolling loop exceed the
// compiler's unroll budget -> runtime-indexed acc[]/wg[] -> scratch spill
// (R2: VGPR=44, 2x WRITE_SIZE, 780us/dispatch). VT=8 is known-good codegen.
// R4: H-blur intermediate planes stored bf16 (halves footprint -> L3 serves
// the 5x redundant vertical reads); vertical blurs process 2 cols/thread
// (ushort2 loads, float2 stores) with interior/edge loop split.

#define HH 1024
#define WW 1024
#define HWSZ (HH * WW)
#define RR 16
#define NT 33
#define EPSF 0.01f
#define VT 8  // rows per block in vertical-blur kernels (do NOT raise: spills)

typedef unsigned short u16;
typedef unsigned int u32;

__device__ __forceinline__ u16 f2bf(float f) {  // round-to-nearest-even
  u32 u = __float_as_uint(f);
  u += 0x7fffu + ((u >> 16) & 1u);
  return (u16)(u >> 16);
}
__device__ __forceinline__ float bflo(u32 v) { return __uint_as_float(v << 16); }
__device__ __forceinline__ float bfhi(u32 v) { return __uint_as_float(v & 0xffff0000u); }

__device__ __forceinline__ void make_wg(float wg[NT]) {
#pragma unroll
  for (int i = 0; i < NT; ++i) {
    const float d = (float)(i - RR);
    wg[i] = __expf(d * d * (-1.0f / 32.0f));  // exp(-0.5*d^2/theta^2), theta=4
  }
}

__device__ __forceinline__ float wsum(const float wg[NT]) {
  float s = 0.0f;
#pragma unroll
  for (int i = 0; i < NT; ++i) s += wg[i];
  return s;
}

// edge-aware 1D window weight at coordinate u in [0, n)
__device__ __forceinline__ float win_w(const float wg[NT], float S, int u, int n) {
  if (u >= RR && u < n - RR) return S;
  float w = 0.0f;
#pragma unroll
  for (int i = 0; i < NT; ++i) {
    const int uu = u - RR + i;
    if (uu >= 0 && uu < n) w += wg[i];
  }
  return w;
}

// ---------------------------------------------------------------------------
// K1: products + horizontal blur. Grid (W/256, H), block 256.
// Writes 25 bf16 planes: [0..2]=I, [3..6]=p, [7..18]=I_c*p_k, [19..24]=I_cI_c'
// ---------------------------------------------------------------------------
__global__ __launch_bounds__(256) void k_prod_hblur(const float* __restrict__ I,
                                                    const float* __restrict__ P,
                                                    u16* __restrict__ HB) {
  __shared__ float sI[3][288];
  __shared__ float sp[4][288];
  const int tid = threadIdx.x;
  const int y = blockIdx.y;
  const int x0 = blockIdx.x * 256;
  {
    const int base = (y * WW + (x0 - RR)) * 3;
    for (int idx = tid; idx < 288 * 3; idx += 256) {
      const int xi = idx / 3;
      const int c = idx - xi * 3;
      const int xx = x0 - RR + xi;
      sI[c][xi] = (xx >= 0 && xx < WW) ? I[base + idx] : 0.0f;
    }
  }
  {
    const int base = (y * WW + (x0 - RR)) * 4;
    for (int idx = tid; idx < 288 * 4; idx += 256) {
      const int xi = idx >> 2;
      const int c = idx & 3;
      const int xx = x0 - RR + xi;
      sp[c][xi] = (xx >= 0 && xx < WW) ? P[base + idx] : 0.0f;
    }
  }
  __syncthreads();

  float wg[NT];
  make_wg(wg);
  float acc[25];
#pragma unroll
  for (int j = 0; j < 25; ++j) acc[j] = 0.0f;

#pragma unroll
  for (int dx = 0; dx < NT; ++dx) {
    const float w = wg[dx];
    const float i0 = sI[0][tid + dx], i1 = sI[1][tid + dx], i2 = sI[2][tid + dx];
    const float p0 = sp[0][tid + dx], p1 = sp[1][tid + dx];
    const float p2 = sp[2][tid + dx], p3 = sp[3][tid + dx];
    const float wi0 = w * i0, wi1 = w * i1, wi2 = w * i2;
    const float wp0 = w * p0, wp1 = w * p1, wp2 = w * p2, wp3 = w * p3;
    acc[0] += wi0; acc[1] += wi1; acc[2] += wi2;
    acc[3] += wp0; acc[4] += wp1; acc[5] += wp2; acc[6] += wp3;
    acc[7]  += i0 * wp0; acc[8]  += i0 * wp1; acc[9]  += i0 * wp2; acc[10] += i0 * wp3;
    acc[11] += i1 * wp0; acc[12] += i1 * wp1; acc[13] += i1 * wp2; acc[14] += i1 * wp3;
    acc[15] += i2 * wp0; acc[16] += i2 * wp1; acc[17] += i2 * wp2; acc[18] += i2 * wp3;
    acc[19] += wi0 * i0; acc[20] += wi0 * i1; acc[21] += wi0 * i2;
    acc[22] += wi1 * i1; acc[23] += wi1 * i2; acc[24] += wi2 * i2;
  }
  const int o = y * WW + x0 + tid;
#pragma unroll
  for (int ch = 0; ch < 25; ++ch) HB[ch * HWSZ + o] = f2bf(acc[ch]);
}

// ---------------------------------------------------------------------------
// K2: vertical blur of bf16 planes (VT=8 rolling, 2 cols/thread) + center
//     subtract + /N -> 25 fp32 mean planes.  Grid (W/512, H/VT, 25), block 256.
// ---------------------------------------------------------------------------
__global__ __launch_bounds__(256) void k_vblur25(const u16* __restrict__ HB,
                                                 const float* __restrict__ I,
                                                 const float* __restrict__ P,
                                                 float* __restrict__ M) {
  const int tid = threadIdx.x;
  const int ch = blockIdx.z;
  const int x = blockIdx.x * 512 + tid * 2;
  const int y0 = blockIdx.y * VT;
  float wg[NT];
  make_wg(wg);
  const float S = wsum(wg);

  float a0[VT], a1[VT];
#pragma unroll
  for (int t = 0; t < VT; ++t) { a0[t] = 0.0f; a1[t] = 0.0f; }

  const u16* src = HB + (size_t)ch * HWSZ + x;
  const bool interior = (y0 >= RR) && (y0 + VT + RR <= HH);
  if (interior) {
    const u16* p0 = src + (size_t)(y0 - RR) * WW;
#pragma unroll
    for (int r = 0; r < VT + 2 * RR; ++r) {
      const u32 v = *reinterpret_cast<const u32*>(p0);
      const float v0 = bflo(v), v1 = bfhi(v);
#pragma unroll
      for (int t = 0; t < VT; ++t) {
        const int dy = r - t;
        if (dy >= 0 && dy < NT) { a0[t] += wg[dy] * v0; a1[t] += wg[dy] * v1; }
      }
      p0 += WW;
    }
  } else {
#pragma unroll
    for (int r = 0; r < VT + 2 * RR; ++r) {
      const int yy = y0 - RR + r;
      float v0 = 0.0f, v1 = 0.0f;
      if (yy >= 0 && yy < HH) {
        const u32 v = *reinterpret_cast<const u32*>(src + (size_t)yy * WW);
        v0 = bflo(v); v1 = bfhi(v);
      }
#pragma unroll
      for (int t = 0; t < VT; ++t) {
        const int dy = r - t;
        if (dy >= 0 && dy < NT) { a0[t] += wg[dy] * v0; a1[t] += wg[dy] * v1; }
      }
    }
  }
  const float rowW0 = win_w(wg, S, x, WW);
  const float rowW1 = win_w(wg, S, x + 1, WW);

  // channel -> center-value decode (wave-uniform)
  int kind, cA, cB;
  if (ch < 3)       { kind = 0; cA = ch;            cB = 0; }
  else if (ch < 7)  { kind = 1; cA = ch - 3;        cB = 0; }
  else if (ch < 19) { kind = 2; cA = (ch - 7) >> 2; cB = (ch - 7) & 3; }
  else {
    kind = 3;
    const int j = ch - 19;  // (0,0)(0,1)(0,2)(1,1)(1,2)(2,2)
    cA = (j < 3) ? 0 : ((j < 5) ? 1 : 2);
    cB = (j == 0) ? 0 : (j == 1 ? 1 : (j == 2 ? 2 : (j == 3 ? 1 : 2)));
  }
#pragma unroll
  for (int t = 0; t < VT; ++t) {
    const int y = y0 + t;
    const float colW = interior ? S : win_w(wg, S, y, HH);
    const int pix = y * WW + x;
    float c0, c1;
    if (kind == 0)      { c0 = I[pix * 3 + cA];                    c1 = I[(pix + 1) * 3 + cA]; }
    else if (kind == 1) { c0 = P[pix * 4 + cA];                    c1 = P[(pix + 1) * 4 + cA]; }
    else if (kind == 2) { c0 = I[pix * 3 + cA] * P[pix * 4 + cB];  c1 = I[(pix + 1) * 3 + cA] * P[(pix + 1) * 4 + cB]; }
    else                { c0 = I[pix * 3 + cA] * I[pix * 3 + cB];  c1 = I[(pix + 1) * 3 + cA] * I[(pix + 1) * 3 + cB]; }
    const float in0 = __builtin_amdgcn_rcpf(rowW0 * colW - 1.0f);
    const float in1 = __builtin_amdgcn_rcpf(rowW1 * colW - 1.0f);
    float2 o;
    o.x = (a0[t] - c0) * in0;
    o.y = (a1[t] - c1) * in1;
    *reinterpret_cast<float2*>(M + (size_t)ch * HWSZ + pix) = o;
  }
}

// ---------------------------------------------------------------------------
// K3: pointwise 3x3 SPD solve with 4 RHS -> 16 planes (a: c*4+k, b: 12+k).
// Grid (HW/256), block 256.
// ---------------------------------------------------------------------------
__global__ __launch_bounds__(256) void k_solve(const float* __restrict__ M,
                                               float* __restrict__ AB) {
  const int i = blockIdx.x * 256 + threadIdx.x;
  const float mI0 = M[i], mI1 = M[HWSZ + i], mI2 = M[2 * HWSZ + i];
  float mp[4];
#pragma unroll
  for (int k = 0; k < 4; ++k) mp[k] = M[(3 + k) * HWSZ + i];
  float cov[12];
#pragma unroll
  for (int j = 0; j < 12; ++j) cov[j] = M[(7 + j) * HWSZ + i];
#pragma unroll
  for (int k = 0; k < 4; ++k) {
    cov[k]     -= mI0 * mp[k];
    cov[4 + k] -= mI1 * mp[k];
    cov[8 + k] -= mI2 * mp[k];
  }
  const float A00 = M[19 * HWSZ + i] - mI0 * mI0 + EPSF;
  const float A01 = M[20 * HWSZ + i] - mI0 * mI1;
  const float A02 = M[21 * HWSZ + i] - mI0 * mI2;
  const float A11 = M[22 * HWSZ + i] - mI1 * mI1 + EPSF;
  const float A12 = M[23 * HWSZ + i] - mI1 * mI2;
  const float A22 = M[24 * HWSZ + i] - mI2 * mI2 + EPSF;
  const float c00 = A11 * A22 - A12 * A12;
  const float c01 = A02 * A12 - A01 * A22;
  const float c02 = A01 * A12 - A02 * A11;
  const float det = A00 * c00 + A01 * c01 + A02 * c02;
  const float idet = 1.0f / det;
  const float i00 = c00 * idet, i01 = c01 * idet, i02 = c02 * idet;
  const float i11 = (A00 * A22 - A02 * A02) * idet;
  const float i12 = (A01 * A02 - A00 * A12) * idet;
  const float i22 = (A00 * A11 - A01 * A01) * idet;
#pragma unroll
  for (int k = 0; k < 4; ++k) {
    const float a0 = i00 * cov[k] + i01 * cov[4 + k] + i02 * cov[8 + k];
    const float a1 = i01 * cov[k] + i11 * cov[4 + k] + i12 * cov[8 + k];
    const float a2 = i02 * cov[k] + i12 * cov[4 + k] + i22 * cov[8 + k];
    AB[k * HWSZ + i] = a0;
    AB[(4 + k) * HWSZ + i] = a1;
    AB[(8 + k) * HWSZ + i] = a2;
    AB[(12 + k) * HWSZ + i] = mp[k] - (a0 * mI0 + a1 * mI1 + a2 * mI2);
  }
}

// ---------------------------------------------------------------------------
// K4: plain horizontal blur of 16 planes -> bf16. Grid (W/256, H, 16).
// ---------------------------------------------------------------------------
__global__ __launch_bounds__(256) void k_hblur16(const float* __restrict__ AB,
                                                 u16* __restrict__ HB) {
  __shared__ float s[288];
  const int tid = threadIdx.x;
  const int ch = blockIdx.z;
  const int y = blockIdx.y;
  const int x0 = blockIdx.x * 256;
  const float* src = AB + (size_t)ch * HWSZ + y * WW;
  for (int idx = tid; idx < 288; idx += 256) {
    const int xx = x0 - RR + idx;
    s[idx] = (xx >= 0 && xx < WW) ? src[xx] : 0.0f;
  }
  __syncthreads();
  float wg[NT];
  make_wg(wg);
  float a = 0.0f;
#pragma unroll
  for (int dx = 0; dx < NT; ++dx) a += wg[dx] * s[tid + dx];
  HB[(size_t)ch * HWSZ + y * WW + x0 + tid] = f2bf(a);
}

// ---------------------------------------------------------------------------
// K5a: vertical blur of 16 bf16 planes (VT=8, 2 cols/thread) + center
//      subtract (in-place on AB) + /N.  Grid (W/512, H/VT, 16), block 256.
//      In-place safe: each thread rmw's only its own addresses.
// ---------------------------------------------------------------------------
__global__ __launch_bounds__(256) void k_vblur16(const u16* __restrict__ HB,
                                                 float* __restrict__ AB) {
  const int tid = threadIdx.x;
  const int ch = blockIdx.z;
  const int x = blockIdx.x * 512 + tid * 2;
  const int y0 = blockIdx.y * VT;
  float wg[NT];
  make_wg(wg);
  const float S = wsum(wg);

  float a0[VT], a1[VT];
#pragma unroll
  for (int t = 0; t < VT; ++t) { a0[t] = 0.0f; a1[t] = 0.0f; }

  const u16* src = HB + (size_t)ch * HWSZ + x;
  const bool interior = (y0 >= RR) && (y0 + VT + RR <= HH);
  if (interior) {
    const u16* p0 = src + (size_t)(y0 - RR) * WW;
#pragma unroll
    for (int r = 0; r < VT + 2 * RR; ++r) {
      const u32 v = *reinterpret_cast<const u32*>(p0);
      const float v0 = bflo(v), v1 = bfhi(v);
#pragma unroll
      for (int t = 0; t < VT; ++t) {
        const int dy = r - t;
        if (dy >= 0 && dy < NT) { a0[t] += wg[dy] * v0; a1[t] += wg[dy] * v1; }
      }
      p0 += WW;
    }
  } else {
#pragma unroll
    for (int r = 0; r < VT + 2 * RR; ++r) {
      const int yy = y0 - RR + r;
      float v0 = 0.0f, v1 = 0.0f;
      if (yy >= 0 && yy < HH) {
        const u32 v = *reinterpret_cast<const u32*>(src + (size_t)yy * WW);
        v0 = bflo(v); v1 = bfhi(v);
      }
#pragma unroll
      for (int t = 0; t < VT; ++t) {
        const int dy = r - t;
        if (dy >= 0 && dy < NT) { a0[t] += wg[dy] * v0; a1[t] += wg[dy] * v1; }
      }
    }
  }
  const float rowW0 = win_w(wg, S, x, WW);
  const float rowW1 = win_w(wg, S, x + 1, WW);
  float* dst = AB + (size_t)ch * HWSZ;
#pragma unroll
  for (int t = 0; t < VT; ++t) {
    const int y = y0 + t;
    const float colW = interior ? S : win_w(wg, S, y, HH);
    const int pix = y * WW + x;
    const float2 c = *reinterpret_cast<const float2*>(dst + pix);
    const float in0 = __builtin_amdgcn_rcpf(rowW0 * colW - 1.0f);
    const float in1 = __builtin_amdgcn_rcpf(rowW1 * colW - 1.0f);
    float2 o;
    o.x = (a0[t] - c.x) * in0;
    o.y = (a1[t] - c.y) * in1;
    *reinterpret_cast<float2*>(dst + pix) = o;
  }
}

// ---------------------------------------------------------------------------
// K5b: pointwise combine q_k = sum_c mean_a[c,k]*I_c + mean_b[k].
//      Grid (HW/256), block 256.
// ---------------------------------------------------------------------------
__global__ __launch_bounds__(256) void k_combine(const float* __restrict__ M2,
                                                 const float* __restrict__ I,
                                                 float* __restrict__ out) {
  const int i = blockIdx.x * 256 + threadIdx.x;
  float m[16];
#pragma unroll
  for (int ch = 0; ch < 16; ++ch) m[ch] = M2[ch * HWSZ + i];
  const float i0 = I[i * 3], i1 = I[i * 3 + 1], i2 = I[i * 3 + 2];
  float4 q;
  q.x = m[0] * i0 + m[4] * i1 + m[8] * i2 + m[12];
  q.y = m[1] * i0 + m[5] * i1 + m[9] * i2 + m[13];
  q.z = m[2] * i0 + m[6] * i1 + m[10] * i2 + m[14];
  q.w = m[3] * i0 + m[7] * i1 + m[11] * i2 + m[15];
  *reinterpret_cast<float4*>(out + (size_t)i * 4) = q;
}

extern "C" void kernel_launch(void* const* d_in, const int* in_sizes, int n_in,
                              void* d_out, int out_size, void* d_ws, size_t ws_size,
                              hipStream_t stream) {
  const float* I = (const float*)d_in[0];
  const float* P = (const float*)d_in[1];
  float* out = (float*)d_out;
  float* buf0 = (float*)d_ws;              // 25 fp32 planes / AB / bf16 HB1
  float* buf1 = buf0 + 25 * (size_t)HWSZ;  // 25 fp32 planes (M) / bf16 HB2
  u16* hb1 = (u16*)buf0;  // bf16 stage-1 H-blur (dead before solve writes AB here)
  u16* hb2 = (u16*)buf1;  // bf16 stage-2 H-blur (overwrites M, dead after solve)

  for (int b = 0; b < 2; ++b) {
    const float* Ib = I + (size_t)b * HWSZ * 3;
    const float* Pb = P + (size_t)b * HWSZ * 4;
    float* outb = out + (size_t)b * HWSZ * 4;

    k_prod_hblur<<<dim3(WW / 256, HH), dim3(256), 0, stream>>>(Ib, Pb, hb1);
    k_vblur25<<<dim3(WW / 512, HH / VT, 25), dim3(256), 0, stream>>>(hb1, Ib, Pb, buf1);
    k_solve<<<dim3(HWSZ / 256), dim3(256), 0, stream>>>(buf1, buf0);
    k_hblur16<<<dim3(WW / 256, HH, 16), dim3(256), 0, stream>>>(buf0, hb2);
    k_vblur16<<<dim3(WW / 512, HH / VT, 16), dim3(256), 0, stream>>>(hb2, buf0);
    k_combine<<<dim3(HWSZ / 256), dim3(256), 0, stream>>>(buf0, Ib, outb);
  }
}

// Round 5
// 529.060 us; speedup vs baseline: 1.0483x; 1.0483x over previous
//
#include <hip/hip_runtime.h>

// Guided filter, B=2, H=W=1024, C=3, K=4, R=16, EPS=0.01.
// gf(x) = Vblur33(Hblur33(x)) - x  (separable Gaussian, center tap removed),
// N(y,x) = rowW(x)*colW(y) - 1 computed in closed form per pixel.
// Workspace requirement: 50 planes * 4 MiB = 209,715,200 bytes.
//
// R2 lesson: VT>8 register-rolling from GLOBAL spills (unroll budget).
// R4 lesson: bf16 halved plane bytes but FETCH stayed 254MB -> y-neighbor
//   blocks get zero L2 reuse (different XCDs); fetch path saturates ~2.6TB/s.
// R5: vertical blurs stage a 64-row x 512-col bf16 tile in LDS (64KB) and
//   emit VT=32 rows as 4 sequential VT=8 register-rolling chunks from LDS.
//   Redundancy 5x -> 2x; edge handling via zero-filled staging.

#define HH 1024
#define WW 1024
#define HWSZ (HH * WW)
#define RR 16
#define NT 33
#define EPSF 0.01f

#define VBY 32                 // output rows per vblur block
#define VROWS (VBY + 2 * RR)   // 64 staged rows
#define VCOLS 512              // columns per vblur block (256 packed u32)

typedef unsigned short u16;
typedef unsigned int u32;

__device__ __forceinline__ u16 f2bf(float f) {  // round-to-nearest-even
  u32 u = __float_as_uint(f);
  u += 0x7fffu + ((u >> 16) & 1u);
  return (u16)(u >> 16);
}
__device__ __forceinline__ float bflo(u32 v) { return __uint_as_float(v << 16); }
__device__ __forceinline__ float bfhi(u32 v) { return __uint_as_float(v & 0xffff0000u); }

__device__ __forceinline__ void make_wg(float wg[NT]) {
#pragma unroll
  for (int i = 0; i < NT; ++i) {
    const float d = (float)(i - RR);
    wg[i] = __expf(d * d * (-1.0f / 32.0f));  // exp(-0.5*d^2/theta^2), theta=4
  }
}

__device__ __forceinline__ float wsum(const float wg[NT]) {
  float s = 0.0f;
#pragma unroll
  for (int i = 0; i < NT; ++i) s += wg[i];
  return s;
}

// edge-aware 1D window weight at coordinate u in [0, n)
__device__ __forceinline__ float win_w(const float wg[NT], float S, int u, int n) {
  if (u >= RR && u < n - RR) return S;
  float w = 0.0f;
#pragma unroll
  for (int i = 0; i < NT; ++i) {
    const int uu = u - RR + i;
    if (uu >= 0 && uu < n) w += wg[i];
  }
  return w;
}

// ---------------------------------------------------------------------------
// K1: products + horizontal blur. Grid (W/256, H), block 256.
// Writes 25 bf16 planes: [0..2]=I, [3..6]=p, [7..18]=I_c*p_k, [19..24]=I_cI_c'
// ---------------------------------------------------------------------------
__global__ __launch_bounds__(256) void k_prod_hblur(const float* __restrict__ I,
                                                    const float* __restrict__ P,
                                                    u16* __restrict__ HB) {
  __shared__ float sI[3][288];
  __shared__ float sp[4][288];
  const int tid = threadIdx.x;
  const int y = blockIdx.y;
  const int x0 = blockIdx.x * 256;
  {
    const int base = (y * WW + (x0 - RR)) * 3;
    for (int idx = tid; idx < 288 * 3; idx += 256) {
      const int xi = idx / 3;
      const int c = idx - xi * 3;
      const int xx = x0 - RR + xi;
      sI[c][xi] = (xx >= 0 && xx < WW) ? I[base + idx] : 0.0f;
    }
  }
  {
    const int base = (y * WW + (x0 - RR)) * 4;
    for (int idx = tid; idx < 288 * 4; idx += 256) {
      const int xi = idx >> 2;
      const int c = idx & 3;
      const int xx = x0 - RR + xi;
      sp[c][xi] = (xx >= 0 && xx < WW) ? P[base + idx] : 0.0f;
    }
  }
  __syncthreads();

  float wg[NT];
  make_wg(wg);
  float acc[25];
#pragma unroll
  for (int j = 0; j < 25; ++j) acc[j] = 0.0f;

#pragma unroll
  for (int dx = 0; dx < NT; ++dx) {
    const float w = wg[dx];
    const float i0 = sI[0][tid + dx], i1 = sI[1][tid + dx], i2 = sI[2][tid + dx];
    const float p0 = sp[0][tid + dx], p1 = sp[1][tid + dx];
    const float p2 = sp[2][tid + dx], p3 = sp[3][tid + dx];
    const float wi0 = w * i0, wi1 = w * i1, wi2 = w * i2;
    const float wp0 = w * p0, wp1 = w * p1, wp2 = w * p2, wp3 = w * p3;
    acc[0] += wi0; acc[1] += wi1; acc[2] += wi2;
    acc[3] += wp0; acc[4] += wp1; acc[5] += wp2; acc[6] += wp3;
    acc[7]  += i0 * wp0; acc[8]  += i0 * wp1; acc[9]  += i0 * wp2; acc[10] += i0 * wp3;
    acc[11] += i1 * wp0; acc[12] += i1 * wp1; acc[13] += i1 * wp2; acc[14] += i1 * wp3;
    acc[15] += i2 * wp0; acc[16] += i2 * wp1; acc[17] += i2 * wp2; acc[18] += i2 * wp3;
    acc[19] += wi0 * i0; acc[20] += wi0 * i1; acc[21] += wi0 * i2;
    acc[22] += wi1 * i1; acc[23] += wi1 * i2; acc[24] += wi2 * i2;
  }
  const int o = y * WW + x0 + tid;
#pragma unroll
  for (int ch = 0; ch < 25; ++ch) HB[ch * HWSZ + o] = f2bf(acc[ch]);
}

// ---------------------------------------------------------------------------
// K2: vertical blur of bf16 planes, LDS-staged 64x512 tile, VT=32 outputs
//     as 4x VT=8 rolling chunks + center subtract + /N -> 25 fp32 mean planes.
//     Grid (W/512, H/32, 25), block 256.
// ---------------------------------------------------------------------------
__global__ __launch_bounds__(256) void k_vblur25(const u16* __restrict__ HB,
                                                 const float* __restrict__ I,
                                                 const float* __restrict__ P,
                                                 float* __restrict__ M) {
  __shared__ u32 s[VROWS][VCOLS / 2];  // 64 x 256 u32 = 64 KiB
  const int tid = threadIdx.x;
  const int ch = blockIdx.z;
  const int xb = blockIdx.x * VCOLS;
  const int y0 = blockIdx.y * VBY;
  const int x = xb + tid * 2;

  // ---- stage 64 rows x 512 cols (zero-filled outside [0,HH)) ----
  {
    const u16* src = HB + (size_t)ch * HWSZ + xb;
    uint4 tmp[16];
#pragma unroll
    for (int it = 0; it < 16; ++it) {
      const int id = it * 256 + tid;
      const int row = id >> 6;          // 0..63
      const int cir = id & 63;          // 16B chunk within row
      const int gy = y0 - RR + row;
      uint4 v = make_uint4(0u, 0u, 0u, 0u);
      if (gy >= 0 && gy < HH)
        v = *reinterpret_cast<const uint4*>(src + (size_t)gy * WW + cir * 8);
      tmp[it] = v;
    }
#pragma unroll
    for (int it = 0; it < 16; ++it) {
      const int id = it * 256 + tid;
      const int row = id >> 6;
      const int cir = id & 63;
      *reinterpret_cast<uint4*>(&s[row][cir * 4]) = tmp[it];
    }
  }
  __syncthreads();

  float wg[NT];
  make_wg(wg);
  const float S = wsum(wg);
  const float rowW0 = win_w(wg, S, x, WW);
  const float rowW1 = win_w(wg, S, x + 1, WW);

  // channel -> center-value decode (wave-uniform)
  int kind, cA, cB;
  if (ch < 3)       { kind = 0; cA = ch;            cB = 0; }
  else if (ch < 7)  { kind = 1; cA = ch - 3;        cB = 0; }
  else if (ch < 19) { kind = 2; cA = (ch - 7) >> 2; cB = (ch - 7) & 3; }
  else {
    kind = 3;
    const int j = ch - 19;  // (0,0)(0,1)(0,2)(1,1)(1,2)(2,2)
    cA = (j < 3) ? 0 : ((j < 5) ? 1 : 2);
    cB = (j == 0) ? 0 : (j == 1 ? 1 : (j == 2 ? 2 : (j == 3 ? 1 : 2)));
  }

  for (int c = 0; c < 4; ++c) {  // 4 chunks of 8 output rows
    float a0[8], a1[8];
#pragma unroll
    for (int t = 0; t < 8; ++t) { a0[t] = 0.0f; a1[t] = 0.0f; }
#pragma unroll
    for (int r = 0; r < 40; ++r) {
      const u32 v = s[8 * c + r][tid];
      const float v0 = bflo(v), v1 = bfhi(v);
#pragma unroll
      for (int t = 0; t < 8; ++t) {
        const int dy = r - t;
        if (dy >= 0 && dy < NT) { a0[t] += wg[dy] * v0; a1[t] += wg[dy] * v1; }
      }
    }
#pragma unroll
    for (int t = 0; t < 8; ++t) {
      const int y = y0 + 8 * c + t;
      const float colW = win_w(wg, S, y, HH);
      const int pix = y * WW + x;
      float c0, c1;
      if (kind == 0)      { c0 = I[pix * 3 + cA];                    c1 = I[(pix + 1) * 3 + cA]; }
      else if (kind == 1) { c0 = P[pix * 4 + cA];                    c1 = P[(pix + 1) * 4 + cA]; }
      else if (kind == 2) { c0 = I[pix * 3 + cA] * P[pix * 4 + cB];  c1 = I[(pix + 1) * 3 + cA] * P[(pix + 1) * 4 + cB]; }
      else                { c0 = I[pix * 3 + cA] * I[pix * 3 + cB];  c1 = I[(pix + 1) * 3 + cA] * I[(pix + 1) * 3 + cB]; }
      const float in0 = __builtin_amdgcn_rcpf(rowW0 * colW - 1.0f);
      const float in1 = __builtin_amdgcn_rcpf(rowW1 * colW - 1.0f);
      float2 o;
      o.x = (a0[t] - c0) * in0;
      o.y = (a1[t] - c1) * in1;
      *reinterpret_cast<float2*>(M + (size_t)ch * HWSZ + pix) = o;
    }
  }
}

// ---------------------------------------------------------------------------
// K3: pointwise 3x3 SPD solve with 4 RHS -> 16 planes (a: c*4+k, b: 12+k).
// Grid (HW/256), block 256.
// ---------------------------------------------------------------------------
__global__ __launch_bounds__(256) void k_solve(const float* __restrict__ M,
                                               float* __restrict__ AB) {
  const int i = blockIdx.x * 256 + threadIdx.x;
  const float mI0 = M[i], mI1 = M[HWSZ + i], mI2 = M[2 * HWSZ + i];
  float mp[4];
#pragma unroll
  for (int k = 0; k < 4; ++k) mp[k] = M[(3 + k) * HWSZ + i];
  float cov[12];
#pragma unroll
  for (int j = 0; j < 12; ++j) cov[j] = M[(7 + j) * HWSZ + i];
#pragma unroll
  for (int k = 0; k < 4; ++k) {
    cov[k]     -= mI0 * mp[k];
    cov[4 + k] -= mI1 * mp[k];
    cov[8 + k] -= mI2 * mp[k];
  }
  const float A00 = M[19 * HWSZ + i] - mI0 * mI0 + EPSF;
  const float A01 = M[20 * HWSZ + i] - mI0 * mI1;
  const float A02 = M[21 * HWSZ + i] - mI0 * mI2;
  const float A11 = M[22 * HWSZ + i] - mI1 * mI1 + EPSF;
  const float A12 = M[23 * HWSZ + i] - mI1 * mI2;
  const float A22 = M[24 * HWSZ + i] - mI2 * mI2 + EPSF;
  const float c00 = A11 * A22 - A12 * A12;
  const float c01 = A02 * A12 - A01 * A22;
  const float c02 = A01 * A12 - A02 * A11;
  const float det = A00 * c00 + A01 * c01 + A02 * c02;
  const float idet = 1.0f / det;
  const float i00 = c00 * idet, i01 = c01 * idet, i02 = c02 * idet;
  const float i11 = (A00 * A22 - A02 * A02) * idet;
  const float i12 = (A01 * A02 - A00 * A12) * idet;
  const float i22 = (A00 * A11 - A01 * A01) * idet;
#pragma unroll
  for (int k = 0; k < 4; ++k) {
    const float a0 = i00 * cov[k] + i01 * cov[4 + k] + i02 * cov[8 + k];
    const float a1 = i01 * cov[k] + i11 * cov[4 + k] + i12 * cov[8 + k];
    const float a2 = i02 * cov[k] + i12 * cov[4 + k] + i22 * cov[8 + k];
    AB[k * HWSZ + i] = a0;
    AB[(4 + k) * HWSZ + i] = a1;
    AB[(8 + k) * HWSZ + i] = a2;
    AB[(12 + k) * HWSZ + i] = mp[k] - (a0 * mI0 + a1 * mI1 + a2 * mI2);
  }
}

// ---------------------------------------------------------------------------
// K4: plain horizontal blur of 16 planes -> bf16. Grid (W/256, H, 16).
// ---------------------------------------------------------------------------
__global__ __launch_bounds__(256) void k_hblur16(const float* __restrict__ AB,
                                                 u16* __restrict__ HB) {
  __shared__ float s[288];
  const int tid = threadIdx.x;
  const int ch = blockIdx.z;
  const int y = blockIdx.y;
  const int x0 = blockIdx.x * 256;
  const float* src = AB + (size_t)ch * HWSZ + y * WW;
  for (int idx = tid; idx < 288; idx += 256) {
    const int xx = x0 - RR + idx;
    s[idx] = (xx >= 0 && xx < WW) ? src[xx] : 0.0f;
  }
  __syncthreads();
  float wg[NT];
  make_wg(wg);
  float a = 0.0f;
#pragma unroll
  for (int dx = 0; dx < NT; ++dx) a += wg[dx] * s[tid + dx];
  HB[(size_t)ch * HWSZ + y * WW + x0 + tid] = f2bf(a);
}

// ---------------------------------------------------------------------------
// K5a: vertical blur of 16 bf16 planes, LDS-staged like K2, + center
//      subtract (in-place on AB) + /N.  Grid (W/512, H/32, 16), block 256.
//      In-place safe: each thread rmw's only its own addresses.
// ---------------------------------------------------------------------------
__global__ __launch_bounds__(256) void k_vblur16(const u16* __restrict__ HB,
                                                 float* __restrict__ AB) {
  __shared__ u32 s[VROWS][VCOLS / 2];  // 64 KiB
  const int tid = threadIdx.x;
  const int ch = blockIdx.z;
  const int xb = blockIdx.x * VCOLS;
  const int y0 = blockIdx.y * VBY;
  const int x = xb + tid * 2;

  {
    const u16* src = HB + (size_t)ch * HWSZ + xb;
    uint4 tmp[16];
#pragma unroll
    for (int it = 0; it < 16; ++it) {
      const int id = it * 256 + tid;
      const int row = id >> 6;
      const int cir = id & 63;
      const int gy = y0 - RR + row;
      uint4 v = make_uint4(0u, 0u, 0u, 0u);
      if (gy >= 0 && gy < HH)
        v = *reinterpret_cast<const uint4*>(src + (size_t)gy * WW + cir * 8);
      tmp[it] = v;
    }
#pragma unroll
    for (int it = 0; it < 16; ++it) {
      const int id = it * 256 + tid;
      const int row = id >> 6;
      const int cir = id & 63;
      *reinterpret_cast<uint4*>(&s[row][cir * 4]) = tmp[it];
    }
  }
  __syncthreads();

  float wg[NT];
  make_wg(wg);
  const float S = wsum(wg);
  const float rowW0 = win_w(wg, S, x, WW);
  const float rowW1 = win_w(wg, S, x + 1, WW);
  float* dst = AB + (size_t)ch * HWSZ;

  for (int c = 0; c < 4; ++c) {
    float a0[8], a1[8];
#pragma unroll
    for (int t = 0; t < 8; ++t) { a0[t] = 0.0f; a1[t] = 0.0f; }
#pragma unroll
    for (int r = 0; r < 40; ++r) {
      const u32 v = s[8 * c + r][tid];
      const float v0 = bflo(v), v1 = bfhi(v);
#pragma unroll
      for (int t = 0; t < 8; ++t) {
        const int dy = r - t;
        if (dy >= 0 && dy < NT) { a0[t] += wg[dy] * v0; a1[t] += wg[dy] * v1; }
      }
    }
#pragma unroll
    for (int t = 0; t < 8; ++t) {
      const int y = y0 + 8 * c + t;
      const float colW = win_w(wg, S, y, HH);
      const int pix = y * WW + x;
      const float2 cv = *reinterpret_cast<const float2*>(dst + pix);
      const float in0 = __builtin_amdgcn_rcpf(rowW0 * colW - 1.0f);
      const float in1 = __builtin_amdgcn_rcpf(rowW1 * colW - 1.0f);
      float2 o;
      o.x = (a0[t] - cv.x) * in0;
      o.y = (a1[t] - cv.y) * in1;
      *reinterpret_cast<float2*>(dst + pix) = o;
    }
  }
}

// ---------------------------------------------------------------------------
// K5b: pointwise combine q_k = sum_c mean_a[c,k]*I_c + mean_b[k].
//      Grid (HW/256), block 256.
// ---------------------------------------------------------------------------
__global__ __launch_bounds__(256) void k_combine(const float* __restrict__ M2,
                                                 const float* __restrict__ I,
                                                 float* __restrict__ out) {
  const int i = blockIdx.x * 256 + threadIdx.x;
  float m[16];
#pragma unroll
  for (int ch = 0; ch < 16; ++ch) m[ch] = M2[ch * HWSZ + i];
  const float i0 = I[i * 3], i1 = I[i * 3 + 1], i2 = I[i * 3 + 2];
  float4 q;
  q.x = m[0] * i0 + m[4] * i1 + m[8] * i2 + m[12];
  q.y = m[1] * i0 + m[5] * i1 + m[9] * i2 + m[13];
  q.z = m[2] * i0 + m[6] * i1 + m[10] * i2 + m[14];
  q.w = m[3] * i0 + m[7] * i1 + m[11] * i2 + m[15];
  *reinterpret_cast<float4*>(out + (size_t)i * 4) = q;
}

extern "C" void kernel_launch(void* const* d_in, const int* in_sizes, int n_in,
                              void* d_out, int out_size, void* d_ws, size_t ws_size,
                              hipStream_t stream) {
  const float* I = (const float*)d_in[0];
  const float* P = (const float*)d_in[1];
  float* out = (float*)d_out;
  float* buf0 = (float*)d_ws;              // 25 fp32 planes / AB / bf16 HB1
  float* buf1 = buf0 + 25 * (size_t)HWSZ;  // 25 fp32 planes (M) / bf16 HB2
  u16* hb1 = (u16*)buf0;  // bf16 stage-1 H-blur (dead before solve writes AB here)
  u16* hb2 = (u16*)buf1;  // bf16 stage-2 H-blur (overwrites M, dead after solve)

  for (int b = 0; b < 2; ++b) {
    const float* Ib = I + (size_t)b * HWSZ * 3;
    const float* Pb = P + (size_t)b * HWSZ * 4;
    float* outb = out + (size_t)b * HWSZ * 4;

    k_prod_hblur<<<dim3(WW / 256, HH), dim3(256), 0, stream>>>(Ib, Pb, hb1);
    k_vblur25<<<dim3(WW / VCOLS, HH / VBY, 25), dim3(256), 0, stream>>>(hb1, Ib, Pb, buf1);
    k_solve<<<dim3(HWSZ / 256), dim3(256), 0, stream>>>(buf1, buf0);
    k_hblur16<<<dim3(WW / 256, HH, 16), dim3(256), 0, stream>>>(buf0, hb2);
    k_vblur16<<<dim3(WW / VCOLS, HH / VBY, 16), dim3(256), 0, stream>>>(hb2, buf0);
    k_combine<<<dim3(HWSZ / 256), dim3(256), 0, stream>>>(buf0, Ib, outb);
  }
}

// Round 6
// 419.065 us; speedup vs baseline: 1.3234x; 1.2625x over previous
//
#include <hip/hip_runtime.h>

// Guided filter, B=2, H=W=1024, C=3, K=4, R=16, EPS=0.01.
// gf(x) = Vblur33(Hblur33(x)) - x  (separable Gaussian, center tap removed),
// N(y,x) = rowW(x)*colW(y) - 1 computed in closed form per pixel.
// Workspace requirement: 50 planes * 4 MiB = 209,715,200 bytes.
//
// R2 lesson: VT>8 register-rolling from GLOBAL spills (unroll budget).
// R4 lesson: fewer bytes/elem didn't cut FETCH: y-neighbor blocks get no L2
//   reuse across XCDs; must cut redundancy structurally (LDS tile).
// R5 lesson: 64KB LDS tile -> 2 blocks/CU -> latency-bound at 17% occupancy.
// R6: 32KB tile (1 u16 col/thread), 4 blocks/CU; center-subtract + /N moved
//   from the latency-bound vblur25 into the BW-bound pointwise k_solve.

#define HH 1024
#define WW 1024
#define HWSZ (HH * WW)
#define RR 16
#define NT 33
#define EPSF 0.01f

#define VBY 32                 // output rows per vblur block
#define VROWS (VBY + 2 * RR)   // 64 staged rows
#define VCOLS 256              // columns per vblur block (one u16 col/thread)

typedef unsigned short u16;
typedef unsigned int u32;

__device__ __forceinline__ u16 f2bf(float f) {  // round-to-nearest-even
  u32 u = __float_as_uint(f);
  u += 0x7fffu + ((u >> 16) & 1u);
  return (u16)(u >> 16);
}
__device__ __forceinline__ float bf2f(u16 v) { return __uint_as_float(((u32)v) << 16); }

__device__ __forceinline__ void make_wg(float wg[NT]) {
#pragma unroll
  for (int i = 0; i < NT; ++i) {
    const float d = (float)(i - RR);
    wg[i] = __expf(d * d * (-1.0f / 32.0f));  // exp(-0.5*d^2/theta^2), theta=4
  }
}

__device__ __forceinline__ float wsum(const float wg[NT]) {
  float s = 0.0f;
#pragma unroll
  for (int i = 0; i < NT; ++i) s += wg[i];
  return s;
}

// edge-aware 1D window weight at coordinate u in [0, n)
__device__ __forceinline__ float win_w(const float wg[NT], float S, int u, int n) {
  if (u >= RR && u < n - RR) return S;
  float w = 0.0f;
#pragma unroll
  for (int i = 0; i < NT; ++i) {
    const int uu = u - RR + i;
    if (uu >= 0 && uu < n) w += wg[i];
  }
  return w;
}

// ---------------------------------------------------------------------------
// K1: products + horizontal blur. Grid (W/256, H), block 256.
// Writes 25 bf16 planes: [0..2]=I, [3..6]=p, [7..18]=I_c*p_k, [19..24]=I_cI_c'
// ---------------------------------------------------------------------------
__global__ __launch_bounds__(256) void k_prod_hblur(const float* __restrict__ I,
                                                    const float* __restrict__ P,
                                                    u16* __restrict__ HB) {
  __shared__ float sI[3][288];
  __shared__ float sp[4][288];
  const int tid = threadIdx.x;
  const int y = blockIdx.y;
  const int x0 = blockIdx.x * 256;
  {
    const int base = (y * WW + (x0 - RR)) * 3;
    for (int idx = tid; idx < 288 * 3; idx += 256) {
      const int xi = idx / 3;
      const int c = idx - xi * 3;
      const int xx = x0 - RR + xi;
      sI[c][xi] = (xx >= 0 && xx < WW) ? I[base + idx] : 0.0f;
    }
  }
  {
    const int base = (y * WW + (x0 - RR)) * 4;
    for (int idx = tid; idx < 288 * 4; idx += 256) {
      const int xi = idx >> 2;
      const int c = idx & 3;
      const int xx = x0 - RR + xi;
      sp[c][xi] = (xx >= 0 && xx < WW) ? P[base + idx] : 0.0f;
    }
  }
  __syncthreads();

  float wg[NT];
  make_wg(wg);
  float acc[25];
#pragma unroll
  for (int j = 0; j < 25; ++j) acc[j] = 0.0f;

#pragma unroll
  for (int dx = 0; dx < NT; ++dx) {
    const float w = wg[dx];
    const float i0 = sI[0][tid + dx], i1 = sI[1][tid + dx], i2 = sI[2][tid + dx];
    const float p0 = sp[0][tid + dx], p1 = sp[1][tid + dx];
    const float p2 = sp[2][tid + dx], p3 = sp[3][tid + dx];
    const float wi0 = w * i0, wi1 = w * i1, wi2 = w * i2;
    const float wp0 = w * p0, wp1 = w * p1, wp2 = w * p2, wp3 = w * p3;
    acc[0] += wi0; acc[1] += wi1; acc[2] += wi2;
    acc[3] += wp0; acc[4] += wp1; acc[5] += wp2; acc[6] += wp3;
    acc[7]  += i0 * wp0; acc[8]  += i0 * wp1; acc[9]  += i0 * wp2; acc[10] += i0 * wp3;
    acc[11] += i1 * wp0; acc[12] += i1 * wp1; acc[13] += i1 * wp2; acc[14] += i1 * wp3;
    acc[15] += i2 * wp0; acc[16] += i2 * wp1; acc[17] += i2 * wp2; acc[18] += i2 * wp3;
    acc[19] += wi0 * i0; acc[20] += wi0 * i1; acc[21] += wi0 * i2;
    acc[22] += wi1 * i1; acc[23] += wi1 * i2; acc[24] += wi2 * i2;
  }
  const int o = y * WW + x0 + tid;
#pragma unroll
  for (int ch = 0; ch < 25; ++ch) HB[ch * HWSZ + o] = f2bf(acc[ch]);
}

// ---------------------------------------------------------------------------
// K2: pure vertical blur of bf16 planes, LDS-staged 64x256 tile (32 KiB),
//     VT=32 outputs as 4x VT=8 rolling chunks -> 25 fp32 raw-blur planes.
//     (center subtract + /N deferred to k_solve.)
//     Grid (W/256, H/32, 25), block 256.
// ---------------------------------------------------------------------------
__global__ __launch_bounds__(256) void k_vblur25(const u16* __restrict__ HB,
                                                 float* __restrict__ M) {
  __shared__ u16 s[VROWS][VCOLS];  // 64 x 256 u16 = 32 KiB
  const int tid = threadIdx.x;
  const int ch = blockIdx.z;
  const int xb = blockIdx.x * VCOLS;
  const int y0 = blockIdx.y * VBY;
  const int x = xb + tid;

  // ---- stage 64 rows x 256 cols (zero-filled outside [0,HH)) ----
  {
    const u16* src = HB + (size_t)ch * HWSZ + xb;
    uint4 tmp[8];
#pragma unroll
    for (int it = 0; it < 8; ++it) {
      const int id = it * 256 + tid;
      const int row = id >> 5;          // 0..63
      const int cir = id & 31;          // 16B chunk within row
      const int gy = y0 - RR + row;
      uint4 v = make_uint4(0u, 0u, 0u, 0u);
      if (gy >= 0 && gy < HH)
        v = *reinterpret_cast<const uint4*>(src + (size_t)gy * WW + cir * 8);
      tmp[it] = v;
    }
#pragma unroll
    for (int it = 0; it < 8; ++it) {
      const int id = it * 256 + tid;
      const int row = id >> 5;
      const int cir = id & 31;
      *reinterpret_cast<uint4*>(&s[row][cir * 8]) = tmp[it];
    }
  }
  __syncthreads();

  float wg[NT];
  make_wg(wg);
  float* dst = M + (size_t)ch * HWSZ;

  for (int c = 0; c < 4; ++c) {  // 4 chunks of 8 output rows
    float a[8];
#pragma unroll
    for (int t = 0; t < 8; ++t) a[t] = 0.0f;
#pragma unroll
    for (int r = 0; r < 40; ++r) {
      const float v = bf2f(s[8 * c + r][tid]);
#pragma unroll
      for (int t = 0; t < 8; ++t) {
        const int dy = r - t;
        if (dy >= 0 && dy < NT) a[t] += wg[dy] * v;
      }
    }
#pragma unroll
    for (int t = 0; t < 8; ++t) {
      const int y = y0 + 8 * c + t;
      dst[y * WW + x] = a[t];
    }
  }
}

// ---------------------------------------------------------------------------
// K3: normalize (center subtract + /N) + pointwise 3x3 SPD solve with 4 RHS
//     -> 16 planes (a: c*4+k, b: 12+k).  Grid (HW/256), block 256.
// ---------------------------------------------------------------------------
__global__ __launch_bounds__(256) void k_solve(const float* __restrict__ M,
                                               const float* __restrict__ I,
                                               const float* __restrict__ P,
                                               float* __restrict__ AB) {
  const int i = blockIdx.x * 256 + threadIdx.x;
  const int y = i >> 10;
  const int x = i & 1023;
  float wg[NT];
  make_wg(wg);
  const float S = wsum(wg);
  const float invN = __builtin_amdgcn_rcpf(win_w(wg, S, x, WW) * win_w(wg, S, y, HH) - 1.0f);

  const float I0 = I[i * 3], I1 = I[i * 3 + 1], I2 = I[i * 3 + 2];
  float p[4];
#pragma unroll
  for (int k = 0; k < 4; ++k) p[k] = P[i * 4 + k];

  const float mI0 = (M[i] - I0) * invN;
  const float mI1 = (M[HWSZ + i] - I1) * invN;
  const float mI2 = (M[2 * HWSZ + i] - I2) * invN;
  float mp[4];
#pragma unroll
  for (int k = 0; k < 4; ++k) mp[k] = (M[(3 + k) * HWSZ + i] - p[k]) * invN;
  float cov[12];
#pragma unroll
  for (int k = 0; k < 4; ++k) {
    cov[k]     = (M[(7 + k) * HWSZ + i]  - I0 * p[k]) * invN - mI0 * mp[k];
    cov[4 + k] = (M[(11 + k) * HWSZ + i] - I1 * p[k]) * invN - mI1 * mp[k];
    cov[8 + k] = (M[(15 + k) * HWSZ + i] - I2 * p[k]) * invN - mI2 * mp[k];
  }
  const float A00 = (M[19 * HWSZ + i] - I0 * I0) * invN - mI0 * mI0 + EPSF;
  const float A01 = (M[20 * HWSZ + i] - I0 * I1) * invN - mI0 * mI1;
  const float A02 = (M[21 * HWSZ + i] - I0 * I2) * invN - mI0 * mI2;
  const float A11 = (M[22 * HWSZ + i] - I1 * I1) * invN - mI1 * mI1 + EPSF;
  const float A12 = (M[23 * HWSZ + i] - I1 * I2) * invN - mI1 * mI2;
  const float A22 = (M[24 * HWSZ + i] - I2 * I2) * invN - mI2 * mI2 + EPSF;
  const float c00 = A11 * A22 - A12 * A12;
  const float c01 = A02 * A12 - A01 * A22;
  const float c02 = A01 * A12 - A02 * A11;
  const float det = A00 * c00 + A01 * c01 + A02 * c02;
  const float idet = 1.0f / det;
  const float i00 = c00 * idet, i01 = c01 * idet, i02 = c02 * idet;
  const float i11 = (A00 * A22 - A02 * A02) * idet;
  const float i12 = (A01 * A02 - A00 * A12) * idet;
  const float i22 = (A00 * A11 - A01 * A01) * idet;
#pragma unroll
  for (int k = 0; k < 4; ++k) {
    const float a0 = i00 * cov[k] + i01 * cov[4 + k] + i02 * cov[8 + k];
    const float a1 = i01 * cov[k] + i11 * cov[4 + k] + i12 * cov[8 + k];
    const float a2 = i02 * cov[k] + i12 * cov[4 + k] + i22 * cov[8 + k];
    AB[k * HWSZ + i] = a0;
    AB[(4 + k) * HWSZ + i] = a1;
    AB[(8 + k) * HWSZ + i] = a2;
    AB[(12 + k) * HWSZ + i] = mp[k] - (a0 * mI0 + a1 * mI1 + a2 * mI2);
  }
}

// ---------------------------------------------------------------------------
// K4: plain horizontal blur of 16 planes -> bf16. Grid (W/256, H, 16).
// ---------------------------------------------------------------------------
__global__ __launch_bounds__(256) void k_hblur16(const float* __restrict__ AB,
                                                 u16* __restrict__ HB) {
  __shared__ float s[288];
  const int tid = threadIdx.x;
  const int ch = blockIdx.z;
  const int y = blockIdx.y;
  const int x0 = blockIdx.x * 256;
  const float* src = AB + (size_t)ch * HWSZ + y * WW;
  for (int idx = tid; idx < 288; idx += 256) {
    const int xx = x0 - RR + idx;
    s[idx] = (xx >= 0 && xx < WW) ? src[xx] : 0.0f;
  }
  __syncthreads();
  float wg[NT];
  make_wg(wg);
  float a = 0.0f;
#pragma unroll
  for (int dx = 0; dx < NT; ++dx) a += wg[dx] * s[tid + dx];
  HB[(size_t)ch * HWSZ + y * WW + x0 + tid] = f2bf(a);
}

// ---------------------------------------------------------------------------
// K5a: vertical blur of 16 bf16 planes, LDS-staged like K2, + center
//      subtract (in-place on AB) + /N.  Grid (W/256, H/32, 16), block 256.
//      In-place safe: each thread rmw's only its own addresses.
// ---------------------------------------------------------------------------
__global__ __launch_bounds__(256) void k_vblur16(const u16* __restrict__ HB,
                                                 float* __restrict__ AB) {
  __shared__ u16 s[VROWS][VCOLS];  // 32 KiB
  const int tid = threadIdx.x;
  const int ch = blockIdx.z;
  const int xb = blockIdx.x * VCOLS;
  const int y0 = blockIdx.y * VBY;
  const int x = xb + tid;

  {
    const u16* src = HB + (size_t)ch * HWSZ + xb;
    uint4 tmp[8];
#pragma unroll
    for (int it = 0; it < 8; ++it) {
      const int id = it * 256 + tid;
      const int row = id >> 5;
      const int cir = id & 31;
      const int gy = y0 - RR + row;
      uint4 v = make_uint4(0u, 0u, 0u, 0u);
      if (gy >= 0 && gy < HH)
        v = *reinterpret_cast<const uint4*>(src + (size_t)gy * WW + cir * 8);
      tmp[it] = v;
    }
#pragma unroll
    for (int it = 0; it < 8; ++it) {
      const int id = it * 256 + tid;
      const int row = id >> 5;
      const int cir = id & 31;
      *reinterpret_cast<uint4*>(&s[row][cir * 8]) = tmp[it];
    }
  }
  __syncthreads();

  float wg[NT];
  make_wg(wg);
  const float S = wsum(wg);
  const float rowW = win_w(wg, S, x, WW);
  float* dst = AB + (size_t)ch * HWSZ;

  for (int c = 0; c < 4; ++c) {
    float a[8];
#pragma unroll
    for (int t = 0; t < 8; ++t) a[t] = 0.0f;
#pragma unroll
    for (int r = 0; r < 40; ++r) {
      const float v = bf2f(s[8 * c + r][tid]);
#pragma unroll
      for (int t = 0; t < 8; ++t) {
        const int dy = r - t;
        if (dy >= 0 && dy < NT) a[t] += wg[dy] * v;
      }
    }
#pragma unroll
    for (int t = 0; t < 8; ++t) {
      const int y = y0 + 8 * c + t;
      const float colW = win_w(wg, S, y, HH);
      const int pix = y * WW + x;
      const float invN = __builtin_amdgcn_rcpf(rowW * colW - 1.0f);
      const float cv = dst[pix];
      dst[pix] = (a[t] - cv) * invN;
    }
  }
}

// ---------------------------------------------------------------------------
// K5b: pointwise combine q_k = sum_c mean_a[c,k]*I_c + mean_b[k].
//      Grid (HW/256), block 256.
// ---------------------------------------------------------------------------
__global__ __launch_bounds__(256) void k_combine(const float* __restrict__ M2,
                                                 const float* __restrict__ I,
                                                 float* __restrict__ out) {
  const int i = blockIdx.x * 256 + threadIdx.x;
  float m[16];
#pragma unroll
  for (int ch = 0; ch < 16; ++ch) m[ch] = M2[ch * HWSZ + i];
  const float i0 = I[i * 3], i1 = I[i * 3 + 1], i2 = I[i * 3 + 2];
  float4 q;
  q.x = m[0] * i0 + m[4] * i1 + m[8] * i2 + m[12];
  q.y = m[1] * i0 + m[5] * i1 + m[9] * i2 + m[13];
  q.z = m[2] * i0 + m[6] * i1 + m[10] * i2 + m[14];
  q.w = m[3] * i0 + m[7] * i1 + m[11] * i2 + m[15];
  *reinterpret_cast<float4*>(out + (size_t)i * 4) = q;
}

extern "C" void kernel_launch(void* const* d_in, const int* in_sizes, int n_in,
                              void* d_out, int out_size, void* d_ws, size_t ws_size,
                              hipStream_t stream) {
  const float* I = (const float*)d_in[0];
  const float* P = (const float*)d_in[1];
  float* out = (float*)d_out;
  float* buf0 = (float*)d_ws;              // 25 fp32 planes / AB / bf16 HB1
  float* buf1 = buf0 + 25 * (size_t)HWSZ;  // 25 fp32 planes (M) / bf16 HB2
  u16* hb1 = (u16*)buf0;  // bf16 stage-1 H-blur (dead before solve writes AB here)
  u16* hb2 = (u16*)buf1;  // bf16 stage-2 H-blur (overwrites M, dead after solve)

  for (int b = 0; b < 2; ++b) {
    const float* Ib = I + (size_t)b * HWSZ * 3;
    const float* Pb = P + (size_t)b * HWSZ * 4;
    float* outb = out + (size_t)b * HWSZ * 4;

    k_prod_hblur<<<dim3(WW / 256, HH), dim3(256), 0, stream>>>(Ib, Pb, hb1);
    k_vblur25<<<dim3(WW / VCOLS, HH / VBY, 25), dim3(256), 0, stream>>>(hb1, buf1);
    k_solve<<<dim3(HWSZ / 256), dim3(256), 0, stream>>>(buf1, Ib, Pb, buf0);
    k_hblur16<<<dim3(WW / 256, HH, 16), dim3(256), 0, stream>>>(buf0, hb2);
    k_vblur16<<<dim3(WW / VCOLS, HH / VBY, 16), dim3(256), 0, stream>>>(hb2, buf0);
    k_combine<<<dim3(HWSZ / 256), dim3(256), 0, stream>>>(buf0, Ib, outb);
  }
}

// Round 7
// 370.232 us; speedup vs baseline: 1.4980x; 1.1319x over previous
//
#include <hip/hip_runtime.h>

// Guided filter, B=2, H=W=1024, C=3, K=4, R=16, EPS=0.01.
// gf(x) = Vblur33(Hblur33(x)) - x  (separable Gaussian, center tap removed),
// N(y,x) = rowW(x)*colW(y) - 1 computed in closed form per pixel.
// Workspace requirement: 50 planes * 4 MiB = 209,715,200 bytes.
//
// R2 lesson: VT>8 register-rolling from GLOBAL spills (unroll budget).
// R4 lesson: fewer bytes/elem didn't cut FETCH; cut redundancy structurally.
// R5 lesson: 64KB LDS tile -> 2 blocks/CU -> latency-bound at 17% occupancy.
// R6 lesson: k_hblur16 was VALU/LDS-issue bound: 33 ds_read_b32 + 33 v_exp
//   per output. R7: whole-row hblur, 4 outputs/thread, float4 LDS reads,
//   and a constexpr Gaussian table (weights become instruction literals).

#define HH 1024
#define WW 1024
#define HWSZ (HH * WW)
#define RR 16
#define NT 33
#define EPSF 0.01f

#define VBY 32                 // output rows per vblur block
#define VROWS (VBY + 2 * RR)   // 64 staged rows
#define VCOLS 256              // columns per vblur block (one u16 col/thread)

typedef unsigned short u16;
typedef unsigned int u32;

// exp(-d^2/32), d = i-16, computed offline (theta = 4).
__device__ constexpr float WG[NT] = {
  0.000335463f, 0.000883827f, 0.002187492f, 0.005086072f, 0.011108997f,
  0.022794173f, 0.043936928f, 0.079559512f, 0.135335283f, 0.216265076f,
  0.324652467f, 0.457833362f, 0.606530660f, 0.754839602f, 0.882496903f,
  0.969233234f, 1.0f,         0.969233234f, 0.882496903f, 0.754839602f,
  0.606530660f, 0.457833362f, 0.324652467f, 0.216265076f, 0.135335283f,
  0.079559512f, 0.043936928f, 0.022794173f, 0.011108997f, 0.005086072f,
  0.002187492f, 0.000883827f, 0.000335463f
};

__device__ constexpr float wg_sum() {
  float s = 0.0f;
  for (int i = 0; i < NT; ++i) s += WG[i];
  return s;
}

__device__ __forceinline__ u16 f2bf(float f) {  // round-to-nearest-even
  u32 u = __float_as_uint(f);
  u += 0x7fffu + ((u >> 16) & 1u);
  return (u16)(u >> 16);
}
__device__ __forceinline__ float bf2f(u16 v) { return __uint_as_float(((u32)v) << 16); }

// edge-aware 1D window weight at coordinate u in [0, n)
__device__ __forceinline__ float win_w(int u, int n) {
  constexpr float S = wg_sum();
  if (u >= RR && u < n - RR) return S;
  float w = 0.0f;
#pragma unroll
  for (int i = 0; i < NT; ++i) {
    const int uu = u - RR + i;
    if (uu >= 0 && uu < n) w += WG[i];
  }
  return w;
}

// ---------------------------------------------------------------------------
// K1: products + horizontal blur. Grid (W/256, H), block 256.
// Writes 25 bf16 planes: [0..2]=I, [3..6]=p, [7..18]=I_c*p_k, [19..24]=I_cI_c'
// ---------------------------------------------------------------------------
__global__ __launch_bounds__(256) void k_prod_hblur(const float* __restrict__ I,
                                                    const float* __restrict__ P,
                                                    u16* __restrict__ HB) {
  __shared__ float sI[3][288];
  __shared__ float sp[4][288];
  const int tid = threadIdx.x;
  const int y = blockIdx.y;
  const int x0 = blockIdx.x * 256;
  {
    const int base = (y * WW + (x0 - RR)) * 3;
    for (int idx = tid; idx < 288 * 3; idx += 256) {
      const int xi = idx / 3;
      const int c = idx - xi * 3;
      const int xx = x0 - RR + xi;
      sI[c][xi] = (xx >= 0 && xx < WW) ? I[base + idx] : 0.0f;
    }
  }
  {
    const int base = (y * WW + (x0 - RR)) * 4;
    for (int idx = tid; idx < 288 * 4; idx += 256) {
      const int xi = idx >> 2;
      const int c = idx & 3;
      const int xx = x0 - RR + xi;
      sp[c][xi] = (xx >= 0 && xx < WW) ? P[base + idx] : 0.0f;
    }
  }
  __syncthreads();

  float acc[25];
#pragma unroll
  for (int j = 0; j < 25; ++j) acc[j] = 0.0f;

#pragma unroll
  for (int dx = 0; dx < NT; ++dx) {
    const float w = WG[dx];
    const float i0 = sI[0][tid + dx], i1 = sI[1][tid + dx], i2 = sI[2][tid + dx];
    const float p0 = sp[0][tid + dx], p1 = sp[1][tid + dx];
    const float p2 = sp[2][tid + dx], p3 = sp[3][tid + dx];
    const float wi0 = w * i0, wi1 = w * i1, wi2 = w * i2;
    const float wp0 = w * p0, wp1 = w * p1, wp2 = w * p2, wp3 = w * p3;
    acc[0] += wi0; acc[1] += wi1; acc[2] += wi2;
    acc[3] += wp0; acc[4] += wp1; acc[5] += wp2; acc[6] += wp3;
    acc[7]  += i0 * wp0; acc[8]  += i0 * wp1; acc[9]  += i0 * wp2; acc[10] += i0 * wp3;
    acc[11] += i1 * wp0; acc[12] += i1 * wp1; acc[13] += i1 * wp2; acc[14] += i1 * wp3;
    acc[15] += i2 * wp0; acc[16] += i2 * wp1; acc[17] += i2 * wp2; acc[18] += i2 * wp3;
    acc[19] += wi0 * i0; acc[20] += wi0 * i1; acc[21] += wi0 * i2;
    acc[22] += wi1 * i1; acc[23] += wi1 * i2; acc[24] += wi2 * i2;
  }
  const int o = y * WW + x0 + tid;
#pragma unroll
  for (int ch = 0; ch < 25; ++ch) HB[ch * HWSZ + o] = f2bf(acc[ch]);
}

// ---------------------------------------------------------------------------
// K2: pure vertical blur of bf16 planes, LDS-staged 64x256 tile (32 KiB),
//     VT=32 outputs as 4x VT=8 rolling chunks -> 25 fp32 raw-blur planes.
//     Grid (W/256, H/32, 25), block 256.
// ---------------------------------------------------------------------------
__global__ __launch_bounds__(256) void k_vblur25(const u16* __restrict__ HB,
                                                 float* __restrict__ M) {
  __shared__ u16 s[VROWS][VCOLS];  // 64 x 256 u16 = 32 KiB
  const int tid = threadIdx.x;
  const int ch = blockIdx.z;
  const int xb = blockIdx.x * VCOLS;
  const int y0 = blockIdx.y * VBY;
  const int x = xb + tid;

  {
    const u16* src = HB + (size_t)ch * HWSZ + xb;
    uint4 tmp[8];
#pragma unroll
    for (int it = 0; it < 8; ++it) {
      const int id = it * 256 + tid;
      const int row = id >> 5;          // 0..63
      const int cir = id & 31;          // 16B chunk within row
      const int gy = y0 - RR + row;
      uint4 v = make_uint4(0u, 0u, 0u, 0u);
      if (gy >= 0 && gy < HH)
        v = *reinterpret_cast<const uint4*>(src + (size_t)gy * WW + cir * 8);
      tmp[it] = v;
    }
#pragma unroll
    for (int it = 0; it < 8; ++it) {
      const int id = it * 256 + tid;
      const int row = id >> 5;
      const int cir = id & 31;
      *reinterpret_cast<uint4*>(&s[row][cir * 8]) = tmp[it];
    }
  }
  __syncthreads();

  float* dst = M + (size_t)ch * HWSZ;

  for (int c = 0; c < 4; ++c) {  // 4 chunks of 8 output rows
    float a[8];
#pragma unroll
    for (int t = 0; t < 8; ++t) a[t] = 0.0f;
#pragma unroll
    for (int r = 0; r < 40; ++r) {
      const float v = bf2f(s[8 * c + r][tid]);
#pragma unroll
      for (int t = 0; t < 8; ++t) {
        const int dy = r - t;
        if (dy >= 0 && dy < NT) a[t] += WG[dy] * v;
      }
    }
#pragma unroll
    for (int t = 0; t < 8; ++t) {
      const int y = y0 + 8 * c + t;
      dst[y * WW + x] = a[t];
    }
  }
}

// ---------------------------------------------------------------------------
// K3: normalize (center subtract + /N) + pointwise 3x3 SPD solve with 4 RHS
//     -> 16 planes (a: c*4+k, b: 12+k).  Grid (HW/256), block 256.
// ---------------------------------------------------------------------------
__global__ __launch_bounds__(256) void k_solve(const float* __restrict__ M,
                                               const float* __restrict__ I,
                                               const float* __restrict__ P,
                                               float* __restrict__ AB) {
  const int i = blockIdx.x * 256 + threadIdx.x;
  const int y = i >> 10;
  const int x = i & 1023;
  const float invN = __builtin_amdgcn_rcpf(win_w(x, WW) * win_w(y, HH) - 1.0f);

  const float I0 = I[i * 3], I1 = I[i * 3 + 1], I2 = I[i * 3 + 2];
  float p[4];
#pragma unroll
  for (int k = 0; k < 4; ++k) p[k] = P[i * 4 + k];

  const float mI0 = (M[i] - I0) * invN;
  const float mI1 = (M[HWSZ + i] - I1) * invN;
  const float mI2 = (M[2 * HWSZ + i] - I2) * invN;
  float mp[4];
#pragma unroll
  for (int k = 0; k < 4; ++k) mp[k] = (M[(3 + k) * HWSZ + i] - p[k]) * invN;
  float cov[12];
#pragma unroll
  for (int k = 0; k < 4; ++k) {
    cov[k]     = (M[(7 + k) * HWSZ + i]  - I0 * p[k]) * invN - mI0 * mp[k];
    cov[4 + k] = (M[(11 + k) * HWSZ + i] - I1 * p[k]) * invN - mI1 * mp[k];
    cov[8 + k] = (M[(15 + k) * HWSZ + i] - I2 * p[k]) * invN - mI2 * mp[k];
  }
  const float A00 = (M[19 * HWSZ + i] - I0 * I0) * invN - mI0 * mI0 + EPSF;
  const float A01 = (M[20 * HWSZ + i] - I0 * I1) * invN - mI0 * mI1;
  const float A02 = (M[21 * HWSZ + i] - I0 * I2) * invN - mI0 * mI2;
  const float A11 = (M[22 * HWSZ + i] - I1 * I1) * invN - mI1 * mI1 + EPSF;
  const float A12 = (M[23 * HWSZ + i] - I1 * I2) * invN - mI1 * mI2;
  const float A22 = (M[24 * HWSZ + i] - I2 * I2) * invN - mI2 * mI2 + EPSF;
  const float c00 = A11 * A22 - A12 * A12;
  const float c01 = A02 * A12 - A01 * A22;
  const float c02 = A01 * A12 - A02 * A11;
  const float det = A00 * c00 + A01 * c01 + A02 * c02;
  const float idet = 1.0f / det;
  const float i00 = c00 * idet, i01 = c01 * idet, i02 = c02 * idet;
  const float i11 = (A00 * A22 - A02 * A02) * idet;
  const float i12 = (A01 * A02 - A00 * A12) * idet;
  const float i22 = (A00 * A11 - A01 * A01) * idet;
#pragma unroll
  for (int k = 0; k < 4; ++k) {
    const float a0 = i00 * cov[k] + i01 * cov[4 + k] + i02 * cov[8 + k];
    const float a1 = i01 * cov[k] + i11 * cov[4 + k] + i12 * cov[8 + k];
    const float a2 = i02 * cov[k] + i12 * cov[4 + k] + i22 * cov[8 + k];
    AB[k * HWSZ + i] = a0;
    AB[(4 + k) * HWSZ + i] = a1;
    AB[(8 + k) * HWSZ + i] = a2;
    AB[(12 + k) * HWSZ + i] = mp[k] - (a0 * mI0 + a1 * mI1 + a2 * mI2);
  }
}

// ---------------------------------------------------------------------------
// K4: horizontal blur of 16 planes -> bf16. One full row per block,
//     4 outputs/thread via float4 LDS reads + register rolling.
//     Grid (H, 16), block 256.
// ---------------------------------------------------------------------------
__global__ __launch_bounds__(256) void k_hblur16(const float* __restrict__ AB,
                                                 u16* __restrict__ HB) {
  __shared__ float s[1056];  // 16 halo | 1024 row | 16 halo
  const int tid = threadIdx.x;
  const int y = blockIdx.x;
  const int ch = blockIdx.y;
  const float* src = AB + (size_t)ch * HWSZ + y * WW;
  if (tid < 16) { s[tid] = 0.0f; s[1040 + tid] = 0.0f; }
  *reinterpret_cast<float4*>(&s[16 + 4 * tid]) =
      *reinterpret_cast<const float4*>(&src[4 * tid]);
  __syncthreads();

  // window for outputs x=4t..4t+3 covers cols 4t-16..4t+19 -> s[4t..4t+35]
  float vals[36];
  {
    const float4* s4 = reinterpret_cast<const float4*>(s) + tid;
#pragma unroll
    for (int r = 0; r < 9; ++r) {
      const float4 q = s4[r];
      vals[4 * r] = q.x; vals[4 * r + 1] = q.y;
      vals[4 * r + 2] = q.z; vals[4 * r + 3] = q.w;
    }
  }
  float acc[4] = {0.0f, 0.0f, 0.0f, 0.0f};
#pragma unroll
  for (int r = 0; r < 36; ++r) {
#pragma unroll
    for (int k = 0; k < 4; ++k) {
      const int dy = r - k;
      if (dy >= 0 && dy < NT) acc[k] += WG[dy] * vals[r];
    }
  }
  const u32 lo = (u32)f2bf(acc[0]) | ((u32)f2bf(acc[1]) << 16);
  const u32 hi = (u32)f2bf(acc[2]) | ((u32)f2bf(acc[3]) << 16);
  *reinterpret_cast<uint2*>(&HB[(size_t)ch * HWSZ + y * WW + 4 * tid]) =
      make_uint2(lo, hi);
}

// ---------------------------------------------------------------------------
// K5a: vertical blur of 16 bf16 planes, LDS-staged like K2, + center
//      subtract (in-place on AB) + /N.  Grid (W/256, H/32, 16), block 256.
//      In-place safe: each thread rmw's only its own addresses.
// ---------------------------------------------------------------------------
__global__ __launch_bounds__(256) void k_vblur16(const u16* __restrict__ HB,
                                                 float* __restrict__ AB) {
  __shared__ u16 s[VROWS][VCOLS];  // 32 KiB
  const int tid = threadIdx.x;
  const int ch = blockIdx.z;
  const int xb = blockIdx.x * VCOLS;
  const int y0 = blockIdx.y * VBY;
  const int x = xb + tid;

  {
    const u16* src = HB + (size_t)ch * HWSZ + xb;
    uint4 tmp[8];
#pragma unroll
    for (int it = 0; it < 8; ++it) {
      const int id = it * 256 + tid;
      const int row = id >> 5;
      const int cir = id & 31;
      const int gy = y0 - RR + row;
      uint4 v = make_uint4(0u, 0u, 0u, 0u);
      if (gy >= 0 && gy < HH)
        v = *reinterpret_cast<const uint4*>(src + (size_t)gy * WW + cir * 8);
      tmp[it] = v;
    }
#pragma unroll
    for (int it = 0; it < 8; ++it) {
      const int id = it * 256 + tid;
      const int row = id >> 5;
      const int cir = id & 31;
      *reinterpret_cast<uint4*>(&s[row][cir * 8]) = tmp[it];
    }
  }
  __syncthreads();

  const float rowW = win_w(x, WW);
  float* dst = AB + (size_t)ch * HWSZ;

  for (int c = 0; c < 4; ++c) {
    float a[8];
#pragma unroll
    for (int t = 0; t < 8; ++t) a[t] = 0.0f;
#pragma unroll
    for (int r = 0; r < 40; ++r) {
      const float v = bf2f(s[8 * c + r][tid]);
#pragma unroll
      for (int t = 0; t < 8; ++t) {
        const int dy = r - t;
        if (dy >= 0 && dy < NT) a[t] += WG[dy] * v;
      }
    }
#pragma unroll
    for (int t = 0; t < 8; ++t) {
      const int y = y0 + 8 * c + t;
      const float colW = win_w(y, HH);
      const int pix = y * WW + x;
      const float invN = __builtin_amdgcn_rcpf(rowW * colW - 1.0f);
      const float cv = dst[pix];
      dst[pix] = (a[t] - cv) * invN;
    }
  }
}

// ---------------------------------------------------------------------------
// K5b: pointwise combine q_k = sum_c mean_a[c,k]*I_c + mean_b[k].
//      Grid (HW/256), block 256.
// ---------------------------------------------------------------------------
__global__ __launch_bounds__(256) void k_combine(const float* __restrict__ M2,
                                                 const float* __restrict__ I,
                                                 float* __restrict__ out) {
  const int i = blockIdx.x * 256 + threadIdx.x;
  float m[16];
#pragma unroll
  for (int ch = 0; ch < 16; ++ch) m[ch] = M2[ch * HWSZ + i];
  const float i0 = I[i * 3], i1 = I[i * 3 + 1], i2 = I[i * 3 + 2];
  float4 q;
  q.x = m[0] * i0 + m[4] * i1 + m[8] * i2 + m[12];
  q.y = m[1] * i0 + m[5] * i1 + m[9] * i2 + m[13];
  q.z = m[2] * i0 + m[6] * i1 + m[10] * i2 + m[14];
  q.w = m[3] * i0 + m[7] * i1 + m[11] * i2 + m[15];
  *reinterpret_cast<float4*>(out + (size_t)i * 4) = q;
}

extern "C" void kernel_launch(void* const* d_in, const int* in_sizes, int n_in,
                              void* d_out, int out_size, void* d_ws, size_t ws_size,
                              hipStream_t stream) {
  const float* I = (const float*)d_in[0];
  const float* P = (const float*)d_in[1];
  float* out = (float*)d_out;
  float* buf0 = (float*)d_ws;              // 25 fp32 planes / AB / bf16 HB1
  float* buf1 = buf0 + 25 * (size_t)HWSZ;  // 25 fp32 planes (M) / bf16 HB2
  u16* hb1 = (u16*)buf0;  // bf16 stage-1 H-blur (dead before solve writes AB here)
  u16* hb2 = (u16*)buf1;  // bf16 stage-2 H-blur (overwrites M, dead after solve)

  for (int b = 0; b < 2; ++b) {
    const float* Ib = I + (size_t)b * HWSZ * 3;
    const float* Pb = P + (size_t)b * HWSZ * 4;
    float* outb = out + (size_t)b * HWSZ * 4;

    k_prod_hblur<<<dim3(WW / 256, HH), dim3(256), 0, stream>>>(Ib, Pb, hb1);
    k_vblur25<<<dim3(WW / VCOLS, HH / VBY, 25), dim3(256), 0, stream>>>(hb1, buf1);
    k_solve<<<dim3(HWSZ / 256), dim3(256), 0, stream>>>(buf1, Ib, Pb, buf0);
    k_hblur16<<<dim3(HH, 16), dim3(256), 0, stream>>>(buf0, hb2);
    k_vblur16<<<dim3(WW / VCOLS, HH / VBY, 16), dim3(256), 0, stream>>>(hb2, buf0);
    k_combine<<<dim3(HWSZ / 256), dim3(256), 0, stream>>>(buf0, Ib, outb);
  }
}

// Round 8
// 294.594 us; speedup vs baseline: 1.8826x; 1.2568x over previous
//
#include <hip/hip_runtime.h>

// Guided filter, B=2, H=W=1024, C=3, K=4, R=16, EPS=0.01.
// gf(x) = Vblur33(Hblur33(x)) - x  (separable Gaussian, center tap removed),
// N(y,x) = rowW(x)*colW(y) - 1 closed form.
// Workspace: buf0 = 25 planes (100MB), buf1 = 25 planes (100MB). 209,715,200 B.
//
// R2: VT>8 register-rolling from GLOBAL spills (unroll budget). Keep 8.
// R4: fewer bytes/elem didn't cut FETCH; cut redundancy structurally (LDS).
// R5: 64KB LDS tile -> 2 blocks/CU -> latency-bound. 32KB is the sweet spot.
// R6: constexpr Gaussian table; center-subtract belongs in pointwise kernels.
// R8: center round-trip deleted algebraically: k_solve emits s0 = sum a*I + b;
//     vblur16 is a pure blur -> bf16; combine does (sum m~*I + m~b - s0)*invN.
//     M planes now bf16 (R3->R4 showed this error class is below threshold).

#define HH 1024
#define WW 1024
#define HWSZ (HH * WW)
#define RR 16
#define NT 33
#define EPSF 0.01f

#define VBY 32                 // output rows per vblur block
#define VROWS (VBY + 2 * RR)   // 64 staged rows
#define VCOLS 256              // columns per vblur block (one u16 col/thread)

typedef unsigned short u16;
typedef unsigned int u32;

// exp(-d^2/32), d = i-16, computed offline (theta = 4).
__device__ constexpr float WG[NT] = {
  0.000335463f, 0.000883827f, 0.002187492f, 0.005086072f, 0.011108997f,
  0.022794173f, 0.043936928f, 0.079559512f, 0.135335283f, 0.216265076f,
  0.324652467f, 0.457833362f, 0.606530660f, 0.754839602f, 0.882496903f,
  0.969233234f, 1.0f,         0.969233234f, 0.882496903f, 0.754839602f,
  0.606530660f, 0.457833362f, 0.324652467f, 0.216265076f, 0.135335283f,
  0.079559512f, 0.043936928f, 0.022794173f, 0.011108997f, 0.005086072f,
  0.002187492f, 0.000883827f, 0.000335463f
};

__device__ constexpr float wg_sum() {
  float s = 0.0f;
  for (int i = 0; i < NT; ++i) s += WG[i];
  return s;
}

__device__ __forceinline__ u16 f2bf(float f) {  // round-to-nearest-even
  u32 u = __float_as_uint(f);
  u += 0x7fffu + ((u >> 16) & 1u);
  return (u16)(u >> 16);
}
__device__ __forceinline__ float bf2f(u16 v) { return __uint_as_float(((u32)v) << 16); }

// edge-aware 1D window weight at coordinate u in [0, n)
__device__ __forceinline__ float win_w(int u, int n) {
  constexpr float S = wg_sum();
  if (u >= RR && u < n - RR) return S;
  float w = 0.0f;
#pragma unroll
  for (int i = 0; i < NT; ++i) {
    const int uu = u - RR + i;
    if (uu >= 0 && uu < n) w += WG[i];
  }
  return w;
}

// ---------------------------------------------------------------------------
// K1: products + horizontal blur. Grid (W/256, H), block 256.
// Writes 25 bf16 planes: [0..2]=I, [3..6]=p, [7..18]=I_c*p_k, [19..24]=I_cI_c'
// ---------------------------------------------------------------------------
__global__ __launch_bounds__(256) void k_prod_hblur(const float* __restrict__ I,
                                                    const float* __restrict__ P,
                                                    u16* __restrict__ HB) {
  __shared__ float sI[3][288];
  __shared__ float sp[4][288];
  const int tid = threadIdx.x;
  const int y = blockIdx.y;
  const int x0 = blockIdx.x * 256;
  {
    const int base = (y * WW + (x0 - RR)) * 3;
    for (int idx = tid; idx < 288 * 3; idx += 256) {
      const int xi = idx / 3;
      const int c = idx - xi * 3;
      const int xx = x0 - RR + xi;
      sI[c][xi] = (xx >= 0 && xx < WW) ? I[base + idx] : 0.0f;
    }
  }
  {
    const int base = (y * WW + (x0 - RR)) * 4;
    for (int idx = tid; idx < 288 * 4; idx += 256) {
      const int xi = idx >> 2;
      const int c = idx & 3;
      const int xx = x0 - RR + xi;
      sp[c][xi] = (xx >= 0 && xx < WW) ? P[base + idx] : 0.0f;
    }
  }
  __syncthreads();

  float acc[25];
#pragma unroll
  for (int j = 0; j < 25; ++j) acc[j] = 0.0f;

#pragma unroll
  for (int dx = 0; dx < NT; ++dx) {
    const float w = WG[dx];
    const float i0 = sI[0][tid + dx], i1 = sI[1][tid + dx], i2 = sI[2][tid + dx];
    const float p0 = sp[0][tid + dx], p1 = sp[1][tid + dx];
    const float p2 = sp[2][tid + dx], p3 = sp[3][tid + dx];
    const float wi0 = w * i0, wi1 = w * i1, wi2 = w * i2;
    const float wp0 = w * p0, wp1 = w * p1, wp2 = w * p2, wp3 = w * p3;
    acc[0] += wi0; acc[1] += wi1; acc[2] += wi2;
    acc[3] += wp0; acc[4] += wp1; acc[5] += wp2; acc[6] += wp3;
    acc[7]  += i0 * wp0; acc[8]  += i0 * wp1; acc[9]  += i0 * wp2; acc[10] += i0 * wp3;
    acc[11] += i1 * wp0; acc[12] += i1 * wp1; acc[13] += i1 * wp2; acc[14] += i1 * wp3;
    acc[15] += i2 * wp0; acc[16] += i2 * wp1; acc[17] += i2 * wp2; acc[18] += i2 * wp3;
    acc[19] += wi0 * i0; acc[20] += wi0 * i1; acc[21] += wi0 * i2;
    acc[22] += wi1 * i1; acc[23] += wi1 * i2; acc[24] += wi2 * i2;
  }
  const int o = y * WW + x0 + tid;
#pragma unroll
  for (int ch = 0; ch < 25; ++ch) HB[ch * HWSZ + o] = f2bf(acc[ch]);
}

// ---------------------------------------------------------------------------
// K2: pure vertical blur of bf16 planes, LDS-staged 64x256 tile (32 KiB),
//     VT=32 outputs as 4x VT=8 rolling chunks -> 25 bf16 raw-blur planes.
//     Grid (W/256, H/32, 25), block 256.
// ---------------------------------------------------------------------------
__global__ __launch_bounds__(256) void k_vblur25(const u16* __restrict__ HB,
                                                 u16* __restrict__ M) {
  __shared__ u16 s[VROWS][VCOLS];  // 64 x 256 u16 = 32 KiB
  const int tid = threadIdx.x;
  const int ch = blockIdx.z;
  const int xb = blockIdx.x * VCOLS;
  const int y0 = blockIdx.y * VBY;
  const int x = xb + tid;

  {
    const u16* src = HB + (size_t)ch * HWSZ + xb;
    uint4 tmp[8];
#pragma unroll
    for (int it = 0; it < 8; ++it) {
      const int id = it * 256 + tid;
      const int row = id >> 5;          // 0..63
      const int cir = id & 31;          // 16B chunk within row
      const int gy = y0 - RR + row;
      uint4 v = make_uint4(0u, 0u, 0u, 0u);
      if (gy >= 0 && gy < HH)
        v = *reinterpret_cast<const uint4*>(src + (size_t)gy * WW + cir * 8);
      tmp[it] = v;
    }
#pragma unroll
    for (int it = 0; it < 8; ++it) {
      const int id = it * 256 + tid;
      const int row = id >> 5;
      const int cir = id & 31;
      *reinterpret_cast<uint4*>(&s[row][cir * 8]) = tmp[it];
    }
  }
  __syncthreads();

  u16* dst = M + (size_t)ch * HWSZ;

  for (int c = 0; c < 4; ++c) {  // 4 chunks of 8 output rows
    float a[8];
#pragma unroll
    for (int t = 0; t < 8; ++t) a[t] = 0.0f;
#pragma unroll
    for (int r = 0; r < 40; ++r) {
      const float v = bf2f(s[8 * c + r][tid]);
#pragma unroll
      for (int t = 0; t < 8; ++t) {
        const int dy = r - t;
        if (dy >= 0 && dy < NT) a[t] += WG[dy] * v;
      }
    }
#pragma unroll
    for (int t = 0; t < 8; ++t) {
      const int y = y0 + 8 * c + t;
      dst[y * WW + x] = f2bf(a[t]);
    }
  }
}

// ---------------------------------------------------------------------------
// K3: normalize (center subtract + /N) + pointwise 3x3 SPD solve with 4 RHS
//     -> 16 fp32 planes (a: c*4+k, b: 12+k) + s0[pix*4+k] = sum_c a*I_c + b.
//     Grid (HW/256), block 256.
// ---------------------------------------------------------------------------
__global__ __launch_bounds__(256) void k_solve(const u16* __restrict__ M,
                                               const float* __restrict__ I,
                                               const float* __restrict__ P,
                                               float* __restrict__ AB,
                                               float* __restrict__ S0) {
  const int i = blockIdx.x * 256 + threadIdx.x;
  const int y = i >> 10;
  const int x = i & 1023;
  const float invN = __builtin_amdgcn_rcpf(win_w(x, WW) * win_w(y, HH) - 1.0f);

  const float I0 = I[i * 3], I1 = I[i * 3 + 1], I2 = I[i * 3 + 2];
  float p[4];
#pragma unroll
  for (int k = 0; k < 4; ++k) p[k] = P[i * 4 + k];

  const float mI0 = (bf2f(M[i]) - I0) * invN;
  const float mI1 = (bf2f(M[HWSZ + i]) - I1) * invN;
  const float mI2 = (bf2f(M[2 * HWSZ + i]) - I2) * invN;
  float mp[4];
#pragma unroll
  for (int k = 0; k < 4; ++k) mp[k] = (bf2f(M[(3 + k) * HWSZ + i]) - p[k]) * invN;
  float cov[12];
#pragma unroll
  for (int k = 0; k < 4; ++k) {
    cov[k]     = (bf2f(M[(7 + k) * HWSZ + i])  - I0 * p[k]) * invN - mI0 * mp[k];
    cov[4 + k] = (bf2f(M[(11 + k) * HWSZ + i]) - I1 * p[k]) * invN - mI1 * mp[k];
    cov[8 + k] = (bf2f(M[(15 + k) * HWSZ + i]) - I2 * p[k]) * invN - mI2 * mp[k];
  }
  const float A00 = (bf2f(M[19 * HWSZ + i]) - I0 * I0) * invN - mI0 * mI0 + EPSF;
  const float A01 = (bf2f(M[20 * HWSZ + i]) - I0 * I1) * invN - mI0 * mI1;
  const float A02 = (bf2f(M[21 * HWSZ + i]) - I0 * I2) * invN - mI0 * mI2;
  const float A11 = (bf2f(M[22 * HWSZ + i]) - I1 * I1) * invN - mI1 * mI1 + EPSF;
  const float A12 = (bf2f(M[23 * HWSZ + i]) - I1 * I2) * invN - mI1 * mI2;
  const float A22 = (bf2f(M[24 * HWSZ + i]) - I2 * I2) * invN - mI2 * mI2 + EPSF;
  const float c00 = A11 * A22 - A12 * A12;
  const float c01 = A02 * A12 - A01 * A22;
  const float c02 = A01 * A12 - A02 * A11;
  const float det = A00 * c00 + A01 * c01 + A02 * c02;
  const float idet = 1.0f / det;
  const float i00 = c00 * idet, i01 = c01 * idet, i02 = c02 * idet;
  const float i11 = (A00 * A22 - A02 * A02) * idet;
  const float i12 = (A01 * A02 - A00 * A12) * idet;
  const float i22 = (A00 * A11 - A01 * A01) * idet;
  float4 s0;
  float* s0p = &s0.x;
#pragma unroll
  for (int k = 0; k < 4; ++k) {
    const float a0 = i00 * cov[k] + i01 * cov[4 + k] + i02 * cov[8 + k];
    const float a1 = i01 * cov[k] + i11 * cov[4 + k] + i12 * cov[8 + k];
    const float a2 = i02 * cov[k] + i12 * cov[4 + k] + i22 * cov[8 + k];
    const float b = mp[k] - (a0 * mI0 + a1 * mI1 + a2 * mI2);
    AB[k * HWSZ + i] = a0;
    AB[(4 + k) * HWSZ + i] = a1;
    AB[(8 + k) * HWSZ + i] = a2;
    AB[(12 + k) * HWSZ + i] = b;
    s0p[k] = a0 * I0 + a1 * I1 + a2 * I2 + b;
  }
  *reinterpret_cast<float4*>(S0 + (size_t)i * 4) = s0;
}

// ---------------------------------------------------------------------------
// K4: horizontal blur of 16 planes -> bf16. One full row per block,
//     4 outputs/thread via float4 LDS reads + register rolling.
//     Grid (H, 16), block 256.
// ---------------------------------------------------------------------------
__global__ __launch_bounds__(256) void k_hblur16(const float* __restrict__ AB,
                                                 u16* __restrict__ HB) {
  __shared__ float s[1056];  // 16 halo | 1024 row | 16 halo
  const int tid = threadIdx.x;
  const int y = blockIdx.x;
  const int ch = blockIdx.y;
  const float* src = AB + (size_t)ch * HWSZ + y * WW;
  if (tid < 16) { s[tid] = 0.0f; s[1040 + tid] = 0.0f; }
  *reinterpret_cast<float4*>(&s[16 + 4 * tid]) =
      *reinterpret_cast<const float4*>(&src[4 * tid]);
  __syncthreads();

  // window for outputs x=4t..4t+3 covers cols 4t-16..4t+19 -> s[4t..4t+35]
  float vals[36];
  {
    const float4* s4 = reinterpret_cast<const float4*>(s) + tid;
#pragma unroll
    for (int r = 0; r < 9; ++r) {
      const float4 q = s4[r];
      vals[4 * r] = q.x; vals[4 * r + 1] = q.y;
      vals[4 * r + 2] = q.z; vals[4 * r + 3] = q.w;
    }
  }
  float acc[4] = {0.0f, 0.0f, 0.0f, 0.0f};
#pragma unroll
  for (int r = 0; r < 36; ++r) {
#pragma unroll
    for (int k = 0; k < 4; ++k) {
      const int dy = r - k;
      if (dy >= 0 && dy < NT) acc[k] += WG[dy] * vals[r];
    }
  }
  const u32 lo = (u32)f2bf(acc[0]) | ((u32)f2bf(acc[1]) << 16);
  const u32 hi = (u32)f2bf(acc[2]) | ((u32)f2bf(acc[3]) << 16);
  *reinterpret_cast<uint2*>(&HB[(size_t)ch * HWSZ + y * WW + 4 * tid]) =
      make_uint2(lo, hi);
}

// ---------------------------------------------------------------------------
// K5a: pure vertical blur of 16 bf16 planes (same structure as K2)
//      -> 16 bf16 raw-blur planes.  Grid (W/256, H/32, 16), block 256.
// ---------------------------------------------------------------------------
__global__ __launch_bounds__(256) void k_vblur16(const u16* __restrict__ HB,
                                                 u16* __restrict__ MB) {
  __shared__ u16 s[VROWS][VCOLS];  // 32 KiB
  const int tid = threadIdx.x;
  const int ch = blockIdx.z;
  const int xb = blockIdx.x * VCOLS;
  const int y0 = blockIdx.y * VBY;
  const int x = xb + tid;

  {
    const u16* src = HB + (size_t)ch * HWSZ + xb;
    uint4 tmp[8];
#pragma unroll
    for (int it = 0; it < 8; ++it) {
      const int id = it * 256 + tid;
      const int row = id >> 5;
      const int cir = id & 31;
      const int gy = y0 - RR + row;
      uint4 v = make_uint4(0u, 0u, 0u, 0u);
      if (gy >= 0 && gy < HH)
        v = *reinterpret_cast<const uint4*>(src + (size_t)gy * WW + cir * 8);
      tmp[it] = v;
    }
#pragma unroll
    for (int it = 0; it < 8; ++it) {
      const int id = it * 256 + tid;
      const int row = id >> 5;
      const int cir = id & 31;
      *reinterpret_cast<uint4*>(&s[row][cir * 8]) = tmp[it];
    }
  }
  __syncthreads();

  u16* dst = MB + (size_t)ch * HWSZ;

  for (int c = 0; c < 4; ++c) {
    float a[8];
#pragma unroll
    for (int t = 0; t < 8; ++t) a[t] = 0.0f;
#pragma unroll
    for (int r = 0; r < 40; ++r) {
      const float v = bf2f(s[8 * c + r][tid]);
#pragma unroll
      for (int t = 0; t < 8; ++t) {
        const int dy = r - t;
        if (dy >= 0 && dy < NT) a[t] += WG[dy] * v;
      }
    }
#pragma unroll
    for (int t = 0; t < 8; ++t) {
      const int y = y0 + 8 * c + t;
      dst[y * WW + x] = f2bf(a[t]);
    }
  }
}

// ---------------------------------------------------------------------------
// K5b: combine q_k = (sum_c m~_a[c,k]*I_c + m~_b[k] - s0_k) * invN.
//      m~ are RAW blurs (bf16); invN applied here.  Grid (HW/256), block 256.
// ---------------------------------------------------------------------------
__global__ __launch_bounds__(256) void k_combine(const u16* __restrict__ MB,
                                                 const float* __restrict__ S0,
                                                 const float* __restrict__ I,
                                                 float* __restrict__ out) {
  const int i = blockIdx.x * 256 + threadIdx.x;
  const int y = i >> 10;
  const int x = i & 1023;
  const float invN = __builtin_amdgcn_rcpf(win_w(x, WW) * win_w(y, HH) - 1.0f);
  float m[16];
#pragma unroll
  for (int ch = 0; ch < 16; ++ch) m[ch] = bf2f(MB[(size_t)ch * HWSZ + i]);
  const float i0 = I[i * 3], i1 = I[i * 3 + 1], i2 = I[i * 3 + 2];
  const float4 s0 = *reinterpret_cast<const float4*>(S0 + (size_t)i * 4);
  float4 q;
  q.x = (m[0] * i0 + m[4] * i1 + m[8]  * i2 + m[12] - s0.x) * invN;
  q.y = (m[1] * i0 + m[5] * i1 + m[9]  * i2 + m[13] - s0.y) * invN;
  q.z = (m[2] * i0 + m[6] * i1 + m[10] * i2 + m[14] - s0.z) * invN;
  q.w = (m[3] * i0 + m[7] * i1 + m[11] * i2 + m[15] - s0.w) * invN;
  *reinterpret_cast<float4*>(out + (size_t)i * 4) = q;
}

extern "C" void kernel_launch(void* const* d_in, const int* in_sizes, int n_in,
                              void* d_out, int out_size, void* d_ws, size_t ws_size,
                              hipStream_t stream) {
  const float* I = (const float*)d_in[0];
  const float* P = (const float*)d_in[1];
  float* out = (float*)d_out;
  float* buf0 = (float*)d_ws;              // 25-plane region
  float* buf1 = buf0 + 25 * (size_t)HWSZ;  // 25-plane region

  // buf0: hb1 (25 bf16, dead after K2) -> AB (16 fp32, planes 0-15) + S0 (4 fp32, planes 16-19)
  // buf1: M (25 bf16, dead after K3) -> hb2 (16 bf16, planes 0-15) + MB (16 bf16, planes 16-31)
  u16* hb1 = (u16*)buf0;
  u16* Mb  = (u16*)buf1;
  float* AB = buf0;
  float* S0 = buf0 + 16 * (size_t)HWSZ;
  u16* hb2 = (u16*)buf1;
  u16* MBp = (u16*)buf1 + 16 * (size_t)HWSZ;

  for (int b = 0; b < 2; ++b) {
    const float* Ib = I + (size_t)b * HWSZ * 3;
    const float* Pb = P + (size_t)b * HWSZ * 4;
    float* outb = out + (size_t)b * HWSZ * 4;

    k_prod_hblur<<<dim3(WW / 256, HH), dim3(256), 0, stream>>>(Ib, Pb, hb1);
    k_vblur25<<<dim3(WW / VCOLS, HH / VBY, 25), dim3(256), 0, stream>>>(hb1, Mb);
    k_solve<<<dim3(HWSZ / 256), dim3(256), 0, stream>>>(Mb, Ib, Pb, AB, S0);
    k_hblur16<<<dim3(HH, 16), dim3(256), 0, stream>>>(AB, hb2);
    k_vblur16<<<dim3(WW / VCOLS, HH / VBY, 16), dim3(256), 0, stream>>>(hb2, MBp);
    k_combine<<<dim3(HWSZ / 256), dim3(256), 0, stream>>>(MBp, S0, Ib, outb);
  }
}